// Round 4
// baseline (1106.103 us; speedup 1.0000x reference)
//
#include <hip/hip_runtime.h>

// MLA: B=2, N=NKV=2048, E=4096, H=16, HD=256, LQ=512, LKV=256
// Round 7: occupancy doubling for flash_mfma.
//  - QBLK 128->64: 16 q-rows/wave, o[16]=64 acc regs (was 128), qf 32 (was 64)
//    -> ~128 total regs/wave, __launch_bounds__(256,4) -> 4 waves/SIMD.
//  - single-buffer LDS 37.4KB (K 16 + V 16 + P 4.6) -> 4 blocks/CU.
//    (R6 dbuf gained ~2%; cross-block overlap replaces it.)
//  - PtL pad 40->36 (stride 18 banks): fixes 4-way conflict on P b16 writes
//    (quad previously collapsed onto one bank -> the residual 1.78e7).
//  - XCD-chunked swizzle: 4 bh per XCD -> K/V L2 reuse within XCD.
//  - K/V involution swizzle + stage geometry identical to R6 (verified).
//  - non-flash pipeline unchanged (gemm_qkv fusion, cvt fusion kept).

#define B_ 2
#define N_ 2048
#define H_ 16
#define HD_ 256
#define LKV_ 256

typedef __attribute__((ext_vector_type(8))) short bf8;           // 8 x bf16 (4 VGPR)
typedef __attribute__((ext_vector_type(4))) float f4;            // MFMA C/D frag
typedef __attribute__((ext_vector_type(4))) unsigned short us4v;
typedef unsigned short u16;

__device__ __forceinline__ u16 f2b(float f) {
  union { float f; unsigned u; } v; v.f = f;
  unsigned r = (v.u + 0x7FFFu + ((v.u >> 16) & 1u)) >> 16;
  return (u16)r;
}

// global -> LDS direct copy, 16B per lane (CK-style addrspace plumbing)
__device__ __forceinline__ void load_lds16(const void* g, void* l) {
  __builtin_amdgcn_global_load_lds(
      (const __attribute__((address_space(1))) unsigned int*)(unsigned long long)(uintptr_t)g,
      (__attribute__((address_space(3))) unsigned int*)(unsigned int)(uintptr_t)l,
      16, 0, 0);
}

// ---------------- fp32 -> bf16 elementwise, two tensors in one launch ----------------
__global__ __launch_bounds__(256) void cvt_bf16_2(const float* __restrict__ a,
                                                  u16* __restrict__ da,
                                                  const float* __restrict__ b,
                                                  u16* __restrict__ db, int n4)
{
  int i = blockIdx.x * 256 + threadIdx.x;
  const float* s; u16* d;
  if (i < n4) { s = a; d = da; } else { s = b; d = db; i -= n4; }
  float4 v = *(const float4*)(s + (size_t)i * 4);
  us4v o = {f2b(v.x), f2b(v.y), f2b(v.z), f2b(v.w)};
  *(us4v*)(d + (size_t)i * 4) = o;
}

// ---------------- fp32 [R,C] -> bf16 [C,R] (weight transpose) ----------------
__global__ __launch_bounds__(256) void cvt_transpose(const float* __restrict__ src,
                                                     u16* __restrict__ dst, int R, int C)
{
  __shared__ float tile[32][33];
  const int t = threadIdx.x;
  const int tr = t & 31, tc = t >> 5;          // 32 x 8
  const int r0 = blockIdx.x * 32, c0 = blockIdx.y * 32;
#pragma unroll
  for (int i = 0; i < 4; ++i)
    tile[tc + i * 8][tr] = src[(size_t)(r0 + tc + i * 8) * C + c0 + tr];
  __syncthreads();
#pragma unroll
  for (int i = 0; i < 4; ++i)
    dst[(size_t)(c0 + tc + i * 8) * R + r0 + tr] = f2b(tile[tr][tc + i * 8]);
}

// ---------------- bf16 MFMA GEMM: C[M,N] = A[M,K] * Bt[N,K]^T ----------------
// 128x128 tile, BK=32, 4 waves each 64x64, 16x16x32 MFMA, global_load_lds staging.
__global__ __launch_bounds__(256) void gemm_bt(
    const u16* __restrict__ A,   // [M,K] bf16
    const u16* __restrict__ Bt,  // [N,K] bf16
    u16* __restrict__ C,         // [M,N] bf16
    int M, int N, int K)
{
  __shared__ u16 As[128 * 32];   // [m][k], contiguous (global_load_lds layout)
  __shared__ u16 Bs[128 * 32];   // [n][k]

  const int t = threadIdx.x;
  const int w = t >> 6, lane = t & 63;
  const int quad = lane >> 4, l16 = lane & 15;
  const int n0 = blockIdx.x * 128, m0 = blockIdx.y * 128;
  const int wm = (w >> 1) * 64, wn = (w & 1) * 64;

  f4 acc[4][4];
#pragma unroll
  for (int mi = 0; mi < 4; ++mi)
#pragma unroll
    for (int ni = 0; ni < 4; ++ni) acc[mi][ni] = (f4){0.f, 0.f, 0.f, 0.f};

  const u16* Ap = A + (size_t)m0 * K;
  const u16* Bp = Bt + (size_t)n0 * K;
  const int srow = t >> 2, spos = (t & 3) * 8;   // chunk c=t: row c>>2, kpos (c&3)*8

  for (int k0 = 0; k0 < K; k0 += 32) {
    __syncthreads();
    load_lds16(Ap + (size_t)srow * K + k0 + spos,        &As[(size_t)t * 8]);
    load_lds16(Ap + (size_t)(srow + 64) * K + k0 + spos, &As[(size_t)(256 + t) * 8]);
    load_lds16(Bp + (size_t)srow * K + k0 + spos,        &Bs[(size_t)t * 8]);
    load_lds16(Bp + (size_t)(srow + 64) * K + k0 + spos, &Bs[(size_t)(256 + t) * 8]);
    __syncthreads();

    bf8 af[4], bfr[4];
#pragma unroll
    for (int mi = 0; mi < 4; ++mi)
      af[mi] = *(const bf8*)(&As[(wm + mi * 16 + l16) * 32 + quad * 8]);
#pragma unroll
    for (int ni = 0; ni < 4; ++ni)
      bfr[ni] = *(const bf8*)(&Bs[(wn + ni * 16 + l16) * 32 + quad * 8]);
#pragma unroll
    for (int mi = 0; mi < 4; ++mi)
#pragma unroll
      for (int ni = 0; ni < 4; ++ni)
        acc[mi][ni] = __builtin_amdgcn_mfma_f32_16x16x32_bf16(af[mi], bfr[ni], acc[mi][ni], 0, 0, 0);
  }

  u16* Cp = C + (size_t)m0 * N + n0;
#pragma unroll
  for (int mi = 0; mi < 4; ++mi)
#pragma unroll
    for (int r = 0; r < 4; ++r) {
      int m = wm + mi * 16 + quad * 4 + r;
#pragma unroll
      for (int ni = 0; ni < 4; ++ni)
        Cp[(size_t)m * N + wn + ni * 16 + l16] = f2b(acc[mi][ni][r]);
    }
}

// ---------------- fused down-projection GEMMs: C_q (N=512) + C_kv (N=256) ----------------
__global__ __launch_bounds__(256) void gemm_qkv(
    const u16* __restrict__ Aq, const u16* __restrict__ Bq, u16* __restrict__ Cq,
    const u16* __restrict__ Ak, const u16* __restrict__ Bk, u16* __restrict__ Ck)
{
  const int K = 4096;
  __shared__ u16 As[128 * 32];   // [m][k]
  __shared__ u16 Bs[64 * 32];    // [n][k]

  const u16* A; const u16* Bt; u16* C; int N, n0;
  if (blockIdx.x < 8) { A = Aq; Bt = Bq; C = Cq; N = 512; n0 = blockIdx.x * 64; }
  else               { A = Ak; Bt = Bk; C = Ck; N = 256; n0 = (blockIdx.x - 8) * 64; }

  const int t = threadIdx.x;
  const int w = t >> 6, lane = t & 63;
  const int quad = lane >> 4, l16 = lane & 15;
  const int m0 = blockIdx.y * 128;
  const int wm = (w >> 1) * 64, wn = (w & 1) * 32;

  f4 acc[4][2];
#pragma unroll
  for (int mi = 0; mi < 4; ++mi)
#pragma unroll
    for (int ni = 0; ni < 2; ++ni) acc[mi][ni] = (f4){0.f, 0.f, 0.f, 0.f};

  const u16* Ap = A + (size_t)m0 * K;
  const u16* Bp = Bt + (size_t)n0 * K;
  const int srow = t >> 2, spos = (t & 3) * 8;

  for (int k0 = 0; k0 < K; k0 += 32) {
    __syncthreads();
    load_lds16(Ap + (size_t)srow * K + k0 + spos,        &As[(size_t)t * 8]);
    load_lds16(Ap + (size_t)(srow + 64) * K + k0 + spos, &As[(size_t)(256 + t) * 8]);
    load_lds16(Bp + (size_t)srow * K + k0 + spos,        &Bs[(size_t)t * 8]);
    __syncthreads();

    bf8 af[4], bfr[2];
#pragma unroll
    for (int mi = 0; mi < 4; ++mi)
      af[mi] = *(const bf8*)(&As[(wm + mi * 16 + l16) * 32 + quad * 8]);
#pragma unroll
    for (int ni = 0; ni < 2; ++ni)
      bfr[ni] = *(const bf8*)(&Bs[(wn + ni * 16 + l16) * 32 + quad * 8]);
#pragma unroll
    for (int mi = 0; mi < 4; ++mi)
#pragma unroll
      for (int ni = 0; ni < 2; ++ni)
        acc[mi][ni] = __builtin_amdgcn_mfma_f32_16x16x32_bf16(af[mi], bfr[ni], acc[mi][ni], 0, 0, 0);
  }

  u16* Cp = C + (size_t)m0 * N + n0;
#pragma unroll
  for (int mi = 0; mi < 4; ++mi)
#pragma unroll
    for (int r = 0; r < 4; ++r) {
      int m = wm + mi * 16 + quad * 4 + r;
#pragma unroll
      for (int ni = 0; ni < 2; ++ni)
        Cp[(size_t)m * N + wn + ni * 16 + l16] = f2b(acc[mi][ni][r]);
    }
}

// ---------------- transpose vupB [B,NKV,H,HD](bf16) -> vupT [B,H,HD,NKV](bf16) ----------------
__global__ __launch_bounds__(256) void transpose_v(const u16* __restrict__ vupB,
                                                   u16* __restrict__ vupT)
{
  __shared__ u16 tile[64][78];
  const int t = threadIdx.x;
  const int key0 = blockIdx.x * 64, d0 = blockIdx.y * 64;
  const int bh = blockIdx.z, b = bh >> 4, h = bh & 15;

#pragma unroll
  for (int i = 0; i < 2; ++i) {
    int c = t + 256 * i;           // 512 chunks
    int key = c >> 3, d8 = c & 7;
    bf8 v = *(const bf8*)(vupB + ((size_t)(b * N_ + key0 + key) * (H_ * HD_)) + h * HD_ + d0 + d8 * 8);
    *(bf8*)(&tile[key][d8 * 8]) = v;
  }
  __syncthreads();
#pragma unroll
  for (int i = 0; i < 2; ++i) {
    int c = t + 256 * i;
    int d = c >> 3, k8 = c & 7;
    bf8 v;
#pragma unroll
    for (int j = 0; j < 8; ++j) v[j] = (short)tile[k8 * 8 + j][d];
    *(bf8*)(vupT + ((size_t)bh * HD_ + d0 + d) * (size_t)N_ + key0 + k8 * 8) = v;
  }
}

// ---------------- flash attention: bf16 MFMA, online softmax ----------------
// QBLK=64 (16 q-rows/wave), single-buffered gload_lds K/V, 37.4KB LDS,
// __launch_bounds__(256,4) -> target 16 waves/CU. XCD-chunked block swizzle.
__global__ __launch_bounds__(256, 4) void flash_mfma(
    const u16* __restrict__ q2b,   // [B,N,H,LKV] bf16
    const u16* __restrict__ ckvb,  // [B,NKV,LKV] bf16
    const u16* __restrict__ vupT,  // [B,H,HD,NKV] bf16
    float* __restrict__ out)       // [B,N,H*HD] fp32
{
  __shared__ u16 KtL[32 * 256];    // linear [key][lkv], 16KB
  __shared__ u16 VtL[256 * 32];    // linear [d][key],   16KB
  __shared__ u16 PtL[64 * 36];     // pad 36 (stride 18 banks), 4.6KB

  const int t = threadIdx.x;
  const int w = t >> 6, lane = t & 63;
  const int quad = lane >> 4, l16 = lane & 15;

  // XCD-chunked swizzle: 1024 blocks = 8 XCDs x (4 bh x 32 n-blocks).
  // Each XCD's resident blocks share 4 K/V sets -> L2 reuse.
  const int wg = blockIdx.x;
  const int xcd = wg & 7, idx = wg >> 3;
  const int bh = xcd * 4 + (idx >> 5);
  const int n0 = (idx & 31) * 64;
  const int b = bh >> 4, h = bh & 15;

  bf8 qf[8];
  {
    const u16* qbase = q2b + (size_t)(b * N_ + n0 + w * 16 + l16) * (H_ * LKV_) + h * LKV_ + quad * 8;
#pragma unroll
    for (int ks = 0; ks < 8; ++ks)
      qf[ks] = *(const bf8*)(qbase + ks * 32);
  }

  f4 o[16];
#pragma unroll
  for (int dt = 0; dt < 16; ++dt) o[dt] = (f4){0.f, 0.f, 0.f, 0.f};
  float ms[4], ls[4];
#pragma unroll
  for (int r = 0; r < 4; ++r) { ms[r] = -1e30f; ls[r] = 0.f; }

  const u16* kgb = ckvb + (size_t)b * N_ * LKV_;
  const u16* vgb = vupT + (size_t)bh * HD_ * N_;

  const int kswz = l16 & 7;                 // K read XOR (row&7)
  const int vq8  = (quad ^ (l16 & 3)) * 8;  // V read col, loop-invariant

  for (int k0 = 0; k0 < N_; k0 += 32) {
    __syncthreads();           // all waves done reading previous tile
    // ---- stage tile (source pre-swizzled, LDS linear: involution) ----
#pragma unroll
    for (int i = 0; i < 4; ++i) {
      int c = i * 256 + t;
      int kr = c >> 5, kc = (c & 31) ^ (kr & 7);
      load_lds16(kgb + (size_t)(k0 + kr) * LKV_ + kc * 8, &KtL[c * 8]);
    }
#pragma unroll
    for (int i = 0; i < 4; ++i) {
      int c = i * 256 + t;
      int vr = c >> 2, vc = (c & 3) ^ (vr & 3);
      load_lds16(vgb + (size_t)vr * N_ + k0 + vc * 8, &VtL[c * 8]);
    }
    __syncthreads();           // drains vmcnt -> DMA complete

    // ---- QK^T from LDS (swizzled read) ----
    f4 sf[2];
    sf[0] = (f4){0,0,0,0}; sf[1] = (f4){0,0,0,0};
    __builtin_amdgcn_s_setprio(1);
#pragma unroll
    for (int nt = 0; nt < 2; ++nt) {
      const u16* kr = &KtL[(nt * 16 + l16) * 256];
#pragma unroll
      for (int ks = 0; ks < 8; ++ks) {
        bf8 kf = *(const bf8*)(kr + (((quad + ks * 4) ^ kswz) << 3));
        sf[nt] = __builtin_amdgcn_mfma_f32_16x16x32_bf16(qf[ks], kf, sf[nt], 0, 0, 0);
      }
    }
    __builtin_amdgcn_s_setprio(0);

    // ---- online softmax (R3 verified form, single mi) ----
    float al[4];
#pragma unroll
    for (int r = 0; r < 4; ++r) {
      float a0 = sf[0][r] * 0.0625f;
      float a1 = sf[1][r] * 0.0625f;
      float mx = fmaxf(a0, a1);
#pragma unroll
      for (int off = 1; off < 16; off <<= 1) mx = fmaxf(mx, __shfl_xor(mx, off, 16));
      float mn = fmaxf(ms[r], mx);
      float p0 = __expf(a0 - mn), p1 = __expf(a1 - mn);
      float sum = p0 + p1;
#pragma unroll
      for (int off = 1; off < 16; off <<= 1) sum += __shfl_xor(sum, off, 16);
      al[r] = __expf(ms[r] - mn);
      ls[r] = ls[r] * al[r] + sum;
      ms[r] = mn;
      int q = w * 16 + quad * 4 + r;
      PtL[q * 36 + l16]      = f2b(p0);
      PtL[q * 36 + 16 + l16] = f2b(p1);
    }
#pragma unroll
    for (int dt = 0; dt < 16; ++dt) {
      o[dt][0] *= al[0]; o[dt][1] *= al[1];
      o[dt][2] *= al[2]; o[dt][3] *= al[3];
    }

    // P round-trip: per-wave-private PtL rows, no barrier needed
    bf8 pf = *(const bf8*)(&PtL[(w * 16 + l16) * 36 + quad * 8]);

    // ---- PV from LDS (swizzled read) ----
    __builtin_amdgcn_s_setprio(1);
#pragma unroll
    for (int dt = 0; dt < 16; ++dt) {
      bf8 vf = *(const bf8*)(&VtL[(dt * 16 + l16) * 32 + vq8]);
      o[dt] = __builtin_amdgcn_mfma_f32_16x16x32_bf16(pf, vf, o[dt], 0, 0, 0);
    }
    __builtin_amdgcn_s_setprio(0);
  }

#pragma unroll
  for (int r = 0; r < 4; ++r) {
    float iv = 1.f / ls[r];
    float* dst = out + (size_t)(b * N_ + n0 + w * 16 + quad * 4 + r) * (H_ * HD_)
                 + h * HD_ + l16;
#pragma unroll
    for (int dt = 0; dt < 16; ++dt) dst[dt * 16] = o[dt][r] * iv;
  }
}

extern "C" void kernel_launch(void* const* d_in, const int* in_sizes, int n_in,
                              void* d_out, int out_size, void* d_ws, size_t ws_size,
                              hipStream_t stream) {
  const float* Q     = (const float*)d_in[0];  // [2,2048,4096]
  const float* Kin   = (const float*)d_in[1];  // [2,2048,4096]
  const float* Wq_d  = (const float*)d_in[2];  // [4096,512]
  const float* W_qk  = (const float*)d_in[3];  // [512,4096]
  const float* Wkv_d = (const float*)d_in[4];  // [4096,256]
  const float* Wv_u  = (const float*)d_in[5];  // [256,4096]
  float* out = (float*)d_out;

  char* ws = (char*)d_ws;
  // aliasing: qbf reused as vupT (qbf dead after C_q GEMM);
  //           kbf reused as vupB (kbf dead after C_kv GEMM). total 114 MB.
  u16* qbf   = (u16*)(ws);                    // 32 MB bf16 [4096,4096]
  u16* vupT  = qbf;                           //        bf16 [B,H,256,2048]
  u16* kbf   = (u16*)(ws + 33554432);         // 32 MB bf16 [4096,4096]
  u16* vupB  = kbf;                           //        bf16 [4096,4096]
  u16* q2b   = (u16*)(ws + 67108864);         // 32 MB bf16 [4096,4096]
  u16* cqb   = (u16*)(ws + 100663296);        //  4 MB bf16 [4096,512]
  u16* ckvb  = (u16*)(ws + 104857600);        //  2 MB bf16 [4096,256]
  u16* wqdT  = (u16*)(ws + 106954752);        //  4 MB bf16 [512,4096]
  u16* wqkT  = (u16*)(ws + 111149056);        //  4 MB bf16 [4096,512]
  u16* wkvdT = (u16*)(ws + 115343360);        //  2 MB bf16 [256,4096]
  u16* wvuT  = (u16*)(ws + 117440512);        //  2 MB bf16 [4096,256]

  // input converts (Q and K in one launch)
  cvt_bf16_2<<<dim3(32768), 256, 0, stream>>>(Q, qbf, Kin, kbf, 4194304);
  // weight convert+transpose: [R,C] fp32 -> [C,R] bf16
  cvt_transpose<<<dim3(128, 16), 256, 0, stream>>>(Wq_d,  wqdT,  4096, 512);
  cvt_transpose<<<dim3(16, 128), 256, 0, stream>>>(W_qk,  wqkT,  512, 4096);
  cvt_transpose<<<dim3(128, 8),  256, 0, stream>>>(Wkv_d, wkvdT, 4096, 256);
  cvt_transpose<<<dim3(8, 128),  256, 0, stream>>>(Wv_u,  wvuT,  256, 4096);

  // C_q = Q @ Wq_d [4096,512] and C_kv = K @ Wkv_d [4096,256], K=4096, one launch
  gemm_qkv<<<dim3(12, 32), 256, 0, stream>>>(qbf, wqdT, cqb, kbf, wkvdT, ckvb);
  // Q2 = C_q @ W_qk          [4096,4096] K=512
  gemm_bt<<<dim3(32, 32), 256, 0, stream>>>(cqb, wqkT, q2b, 4096, 4096, 512);
  // V_up = C_kv @ Wv_u       [4096,4096] K=256   (overwrites kbf region)
  gemm_bt<<<dim3(32, 32), 256, 0, stream>>>(ckvb, wvuT, vupB, 4096, 4096, 256);
  // V transpose (overwrites qbf region)
  transpose_v<<<dim3(32, 4, 32), 256, 0, stream>>>(vupB, vupT);
  // flash attention: QBLK=64 -> 32 n-blocks x 32 bh = 1024 blocks (XCD-swizzled)
  flash_mfma<<<dim3(1024), 256, 0, stream>>>(q2b, ckvb, vupT, out);
}

// Round 5
// 656.712 us; speedup vs baseline: 1.6843x; 1.6843x over previous
//
#include <hip/hip_runtime.h>

// MLA: B=2, N=NKV=2048, E=4096, H=16, HD=256, LQ=512, LKV=256
// Round 8: R7 spill fix. R7's __launch_bounds__(256,4) forced the 128-reg
//   tier: o[16]=64 AGPR left only 64 arch VGPRs -> ~20 spill slots/thread
//   -> 1.4GB scratch writes + 1.95GB fetch (L3 evicted) -> HBM-bound 792us.
//   Fix: __launch_bounds__(256,3) -> 170-reg tier (3 waves/SIMD, 12
//   waves/CU, 37.5% occ) with ~106 arch VGPRs available -> no spills.
//   Geometry otherwise identical to R7 (correctness-verified): QBLK=64,
//   single-buffer LDS 37.4KB (3 blocks/CU), K/V involution swizzles,
//   PtL pad 36, XCD-chunked block swizzle.
//   Non-flash pipeline unchanged (gemm_qkv fusion, cvt fusion).

#define B_ 2
#define N_ 2048
#define H_ 16
#define HD_ 256
#define LKV_ 256

typedef __attribute__((ext_vector_type(8))) short bf8;           // 8 x bf16 (4 VGPR)
typedef __attribute__((ext_vector_type(4))) float f4;            // MFMA C/D frag
typedef __attribute__((ext_vector_type(4))) unsigned short us4v;
typedef unsigned short u16;

__device__ __forceinline__ u16 f2b(float f) {
  union { float f; unsigned u; } v; v.f = f;
  unsigned r = (v.u + 0x7FFFu + ((v.u >> 16) & 1u)) >> 16;
  return (u16)r;
}

// global -> LDS direct copy, 16B per lane (CK-style addrspace plumbing)
__device__ __forceinline__ void load_lds16(const void* g, void* l) {
  __builtin_amdgcn_global_load_lds(
      (const __attribute__((address_space(1))) unsigned int*)(unsigned long long)(uintptr_t)g,
      (__attribute__((address_space(3))) unsigned int*)(unsigned int)(uintptr_t)l,
      16, 0, 0);
}

// ---------------- fp32 -> bf16 elementwise, two tensors in one launch ----------------
__global__ __launch_bounds__(256) void cvt_bf16_2(const float* __restrict__ a,
                                                  u16* __restrict__ da,
                                                  const float* __restrict__ b,
                                                  u16* __restrict__ db, int n4)
{
  int i = blockIdx.x * 256 + threadIdx.x;
  const float* s; u16* d;
  if (i < n4) { s = a; d = da; } else { s = b; d = db; i -= n4; }
  float4 v = *(const float4*)(s + (size_t)i * 4);
  us4v o = {f2b(v.x), f2b(v.y), f2b(v.z), f2b(v.w)};
  *(us4v*)(d + (size_t)i * 4) = o;
}

// ---------------- fp32 [R,C] -> bf16 [C,R] (weight transpose) ----------------
__global__ __launch_bounds__(256) void cvt_transpose(const float* __restrict__ src,
                                                     u16* __restrict__ dst, int R, int C)
{
  __shared__ float tile[32][33];
  const int t = threadIdx.x;
  const int tr = t & 31, tc = t >> 5;          // 32 x 8
  const int r0 = blockIdx.x * 32, c0 = blockIdx.y * 32;
#pragma unroll
  for (int i = 0; i < 4; ++i)
    tile[tc + i * 8][tr] = src[(size_t)(r0 + tc + i * 8) * C + c0 + tr];
  __syncthreads();
#pragma unroll
  for (int i = 0; i < 4; ++i)
    dst[(size_t)(c0 + tc + i * 8) * R + r0 + tr] = f2b(tile[tr][tc + i * 8]);
}

// ---------------- bf16 MFMA GEMM: C[M,N] = A[M,K] * Bt[N,K]^T ----------------
// 128x128 tile, BK=32, 4 waves each 64x64, 16x16x32 MFMA, global_load_lds staging.
__global__ __launch_bounds__(256) void gemm_bt(
    const u16* __restrict__ A,   // [M,K] bf16
    const u16* __restrict__ Bt,  // [N,K] bf16
    u16* __restrict__ C,         // [M,N] bf16
    int M, int N, int K)
{
  __shared__ u16 As[128 * 32];   // [m][k], contiguous (global_load_lds layout)
  __shared__ u16 Bs[128 * 32];   // [n][k]

  const int t = threadIdx.x;
  const int w = t >> 6, lane = t & 63;
  const int quad = lane >> 4, l16 = lane & 15;
  const int n0 = blockIdx.x * 128, m0 = blockIdx.y * 128;
  const int wm = (w >> 1) * 64, wn = (w & 1) * 64;

  f4 acc[4][4];
#pragma unroll
  for (int mi = 0; mi < 4; ++mi)
#pragma unroll
    for (int ni = 0; ni < 4; ++ni) acc[mi][ni] = (f4){0.f, 0.f, 0.f, 0.f};

  const u16* Ap = A + (size_t)m0 * K;
  const u16* Bp = Bt + (size_t)n0 * K;
  const int srow = t >> 2, spos = (t & 3) * 8;   // chunk c=t: row c>>2, kpos (c&3)*8

  for (int k0 = 0; k0 < K; k0 += 32) {
    __syncthreads();
    load_lds16(Ap + (size_t)srow * K + k0 + spos,        &As[(size_t)t * 8]);
    load_lds16(Ap + (size_t)(srow + 64) * K + k0 + spos, &As[(size_t)(256 + t) * 8]);
    load_lds16(Bp + (size_t)srow * K + k0 + spos,        &Bs[(size_t)t * 8]);
    load_lds16(Bp + (size_t)(srow + 64) * K + k0 + spos, &Bs[(size_t)(256 + t) * 8]);
    __syncthreads();

    bf8 af[4], bfr[4];
#pragma unroll
    for (int mi = 0; mi < 4; ++mi)
      af[mi] = *(const bf8*)(&As[(wm + mi * 16 + l16) * 32 + quad * 8]);
#pragma unroll
    for (int ni = 0; ni < 4; ++ni)
      bfr[ni] = *(const bf8*)(&Bs[(wn + ni * 16 + l16) * 32 + quad * 8]);
#pragma unroll
    for (int mi = 0; mi < 4; ++mi)
#pragma unroll
      for (int ni = 0; ni < 4; ++ni)
        acc[mi][ni] = __builtin_amdgcn_mfma_f32_16x16x32_bf16(af[mi], bfr[ni], acc[mi][ni], 0, 0, 0);
  }

  u16* Cp = C + (size_t)m0 * N + n0;
#pragma unroll
  for (int mi = 0; mi < 4; ++mi)
#pragma unroll
    for (int r = 0; r < 4; ++r) {
      int m = wm + mi * 16 + quad * 4 + r;
#pragma unroll
      for (int ni = 0; ni < 4; ++ni)
        Cp[(size_t)m * N + wn + ni * 16 + l16] = f2b(acc[mi][ni][r]);
    }
}

// ---------------- fused down-projection GEMMs: C_q (N=512) + C_kv (N=256) ----------------
__global__ __launch_bounds__(256) void gemm_qkv(
    const u16* __restrict__ Aq, const u16* __restrict__ Bq, u16* __restrict__ Cq,
    const u16* __restrict__ Ak, const u16* __restrict__ Bk, u16* __restrict__ Ck)
{
  const int K = 4096;
  __shared__ u16 As[128 * 32];   // [m][k]
  __shared__ u16 Bs[64 * 32];    // [n][k]

  const u16* A; const u16* Bt; u16* C; int N, n0;
  if (blockIdx.x < 8) { A = Aq; Bt = Bq; C = Cq; N = 512; n0 = blockIdx.x * 64; }
  else               { A = Ak; Bt = Bk; C = Ck; N = 256; n0 = (blockIdx.x - 8) * 64; }

  const int t = threadIdx.x;
  const int w = t >> 6, lane = t & 63;
  const int quad = lane >> 4, l16 = lane & 15;
  const int m0 = blockIdx.y * 128;
  const int wm = (w >> 1) * 64, wn = (w & 1) * 32;

  f4 acc[4][2];
#pragma unroll
  for (int mi = 0; mi < 4; ++mi)
#pragma unroll
    for (int ni = 0; ni < 2; ++ni) acc[mi][ni] = (f4){0.f, 0.f, 0.f, 0.f};

  const u16* Ap = A + (size_t)m0 * K;
  const u16* Bp = Bt + (size_t)n0 * K;
  const int srow = t >> 2, spos = (t & 3) * 8;

  for (int k0 = 0; k0 < K; k0 += 32) {
    __syncthreads();
    load_lds16(Ap + (size_t)srow * K + k0 + spos,        &As[(size_t)t * 8]);
    load_lds16(Ap + (size_t)(srow + 64) * K + k0 + spos, &As[(size_t)(256 + t) * 8]);
    load_lds16(Bp + (size_t)srow * K + k0 + spos,        &Bs[(size_t)t * 8]);
    __syncthreads();

    bf8 af[4], bfr[2];
#pragma unroll
    for (int mi = 0; mi < 4; ++mi)
      af[mi] = *(const bf8*)(&As[(wm + mi * 16 + l16) * 32 + quad * 8]);
#pragma unroll
    for (int ni = 0; ni < 2; ++ni)
      bfr[ni] = *(const bf8*)(&Bs[(wn + ni * 16 + l16) * 32 + quad * 8]);
#pragma unroll
    for (int mi = 0; mi < 4; ++mi)
#pragma unroll
      for (int ni = 0; ni < 2; ++ni)
        acc[mi][ni] = __builtin_amdgcn_mfma_f32_16x16x32_bf16(af[mi], bfr[ni], acc[mi][ni], 0, 0, 0);
  }

  u16* Cp = C + (size_t)m0 * N + n0;
#pragma unroll
  for (int mi = 0; mi < 4; ++mi)
#pragma unroll
    for (int r = 0; r < 4; ++r) {
      int m = wm + mi * 16 + quad * 4 + r;
#pragma unroll
      for (int ni = 0; ni < 2; ++ni)
        Cp[(size_t)m * N + wn + ni * 16 + l16] = f2b(acc[mi][ni][r]);
    }
}

// ---------------- transpose vupB [B,NKV,H,HD](bf16) -> vupT [B,H,HD,NKV](bf16) ----------------
__global__ __launch_bounds__(256) void transpose_v(const u16* __restrict__ vupB,
                                                   u16* __restrict__ vupT)
{
  __shared__ u16 tile[64][78];
  const int t = threadIdx.x;
  const int key0 = blockIdx.x * 64, d0 = blockIdx.y * 64;
  const int bh = blockIdx.z, b = bh >> 4, h = bh & 15;

#pragma unroll
  for (int i = 0; i < 2; ++i) {
    int c = t + 256 * i;           // 512 chunks
    int key = c >> 3, d8 = c & 7;
    bf8 v = *(const bf8*)(vupB + ((size_t)(b * N_ + key0 + key) * (H_ * HD_)) + h * HD_ + d0 + d8 * 8);
    *(bf8*)(&tile[key][d8 * 8]) = v;
  }
  __syncthreads();
#pragma unroll
  for (int i = 0; i < 2; ++i) {
    int c = t + 256 * i;
    int d = c >> 3, k8 = c & 7;
    bf8 v;
#pragma unroll
    for (int j = 0; j < 8; ++j) v[j] = (short)tile[k8 * 8 + j][d];
    *(bf8*)(vupT + ((size_t)bh * HD_ + d0 + d) * (size_t)N_ + key0 + k8 * 8) = v;
  }
}

// ---------------- flash attention: bf16 MFMA, online softmax ----------------
// QBLK=64 (16 q-rows/wave), single-buffered gload_lds K/V, 37.4KB LDS.
// __launch_bounds__(256,3): 170-reg tier -> 3 waves/SIMD (12 waves/CU) with
// no spills (R7's (256,4) forced 128 regs -> 1.4GB scratch).
__global__ __launch_bounds__(256, 3) void flash_mfma(
    const u16* __restrict__ q2b,   // [B,N,H,LKV] bf16
    const u16* __restrict__ ckvb,  // [B,NKV,LKV] bf16
    const u16* __restrict__ vupT,  // [B,H,HD,NKV] bf16
    float* __restrict__ out)       // [B,N,H*HD] fp32
{
  __shared__ u16 KtL[32 * 256];    // linear [key][lkv], 16KB
  __shared__ u16 VtL[256 * 32];    // linear [d][key],   16KB
  __shared__ u16 PtL[64 * 36];     // pad 36 (stride 18 banks), 4.6KB

  const int t = threadIdx.x;
  const int w = t >> 6, lane = t & 63;
  const int quad = lane >> 4, l16 = lane & 15;

  // XCD-chunked swizzle: 1024 blocks = 8 XCDs x (4 bh x 32 n-blocks).
  const int wg = blockIdx.x;
  const int xcd = wg & 7, idx = wg >> 3;
  const int bh = xcd * 4 + (idx >> 5);
  const int n0 = (idx & 31) * 64;
  const int b = bh >> 4, h = bh & 15;

  bf8 qf[8];
  {
    const u16* qbase = q2b + (size_t)(b * N_ + n0 + w * 16 + l16) * (H_ * LKV_) + h * LKV_ + quad * 8;
#pragma unroll
    for (int ks = 0; ks < 8; ++ks)
      qf[ks] = *(const bf8*)(qbase + ks * 32);
  }

  f4 o[16];
#pragma unroll
  for (int dt = 0; dt < 16; ++dt) o[dt] = (f4){0.f, 0.f, 0.f, 0.f};
  float ms[4], ls[4];
#pragma unroll
  for (int r = 0; r < 4; ++r) { ms[r] = -1e30f; ls[r] = 0.f; }

  const u16* kgb = ckvb + (size_t)b * N_ * LKV_;
  const u16* vgb = vupT + (size_t)bh * HD_ * N_;

  const int kswz = l16 & 7;                 // K read XOR (row&7)
  const int vq8  = (quad ^ (l16 & 3)) * 8;  // V read col, loop-invariant

  for (int k0 = 0; k0 < N_; k0 += 32) {
    __syncthreads();           // all waves done reading previous tile
    // ---- stage tile (source pre-swizzled, LDS linear: involution) ----
#pragma unroll
    for (int i = 0; i < 4; ++i) {
      int c = i * 256 + t;
      int kr = c >> 5, kc = (c & 31) ^ (kr & 7);
      load_lds16(kgb + (size_t)(k0 + kr) * LKV_ + kc * 8, &KtL[c * 8]);
    }
#pragma unroll
    for (int i = 0; i < 4; ++i) {
      int c = i * 256 + t;
      int vr = c >> 2, vc = (c & 3) ^ (vr & 3);
      load_lds16(vgb + (size_t)vr * N_ + k0 + vc * 8, &VtL[c * 8]);
    }
    __syncthreads();           // drains vmcnt -> DMA complete

    // ---- QK^T from LDS (swizzled read) ----
    f4 sf[2];
    sf[0] = (f4){0,0,0,0}; sf[1] = (f4){0,0,0,0};
    __builtin_amdgcn_s_setprio(1);
#pragma unroll
    for (int nt = 0; nt < 2; ++nt) {
      const u16* kr = &KtL[(nt * 16 + l16) * 256];
#pragma unroll
      for (int ks = 0; ks < 8; ++ks) {
        bf8 kf = *(const bf8*)(kr + (((quad + ks * 4) ^ kswz) << 3));
        sf[nt] = __builtin_amdgcn_mfma_f32_16x16x32_bf16(qf[ks], kf, sf[nt], 0, 0, 0);
      }
    }
    __builtin_amdgcn_s_setprio(0);

    // ---- online softmax (R3 verified form, single mi) ----
    float al[4];
#pragma unroll
    for (int r = 0; r < 4; ++r) {
      float a0 = sf[0][r] * 0.0625f;
      float a1 = sf[1][r] * 0.0625f;
      float mx = fmaxf(a0, a1);
#pragma unroll
      for (int off = 1; off < 16; off <<= 1) mx = fmaxf(mx, __shfl_xor(mx, off, 16));
      float mn = fmaxf(ms[r], mx);
      float p0 = __expf(a0 - mn), p1 = __expf(a1 - mn);
      float sum = p0 + p1;
#pragma unroll
      for (int off = 1; off < 16; off <<= 1) sum += __shfl_xor(sum, off, 16);
      al[r] = __expf(ms[r] - mn);
      ls[r] = ls[r] * al[r] + sum;
      ms[r] = mn;
      int q = w * 16 + quad * 4 + r;
      PtL[q * 36 + l16]      = f2b(p0);
      PtL[q * 36 + 16 + l16] = f2b(p1);
    }
#pragma unroll
    for (int dt = 0; dt < 16; ++dt) {
      o[dt][0] *= al[0]; o[dt][1] *= al[1];
      o[dt][2] *= al[2]; o[dt][3] *= al[3];
    }

    // P round-trip: per-wave-private PtL rows, no barrier needed
    bf8 pf = *(const bf8*)(&PtL[(w * 16 + l16) * 36 + quad * 8]);

    // ---- PV from LDS (swizzled read) ----
    __builtin_amdgcn_s_setprio(1);
#pragma unroll
    for (int dt = 0; dt < 16; ++dt) {
      bf8 vf = *(const bf8*)(&VtL[(dt * 16 + l16) * 32 + vq8]);
      o[dt] = __builtin_amdgcn_mfma_f32_16x16x32_bf16(pf, vf, o[dt], 0, 0, 0);
    }
    __builtin_amdgcn_s_setprio(0);
  }

#pragma unroll
  for (int r = 0; r < 4; ++r) {
    float iv = 1.f / ls[r];
    float* dst = out + (size_t)(b * N_ + n0 + w * 16 + quad * 4 + r) * (H_ * HD_)
                 + h * HD_ + l16;
#pragma unroll
    for (int dt = 0; dt < 16; ++dt) dst[dt * 16] = o[dt][r] * iv;
  }
}

extern "C" void kernel_launch(void* const* d_in, const int* in_sizes, int n_in,
                              void* d_out, int out_size, void* d_ws, size_t ws_size,
                              hipStream_t stream) {
  const float* Q     = (const float*)d_in[0];  // [2,2048,4096]
  const float* Kin   = (const float*)d_in[1];  // [2,2048,4096]
  const float* Wq_d  = (const float*)d_in[2];  // [4096,512]
  const float* W_qk  = (const float*)d_in[3];  // [512,4096]
  const float* Wkv_d = (const float*)d_in[4];  // [4096,256]
  const float* Wv_u  = (const float*)d_in[5];  // [256,4096]
  float* out = (float*)d_out;

  char* ws = (char*)d_ws;
  // aliasing: qbf reused as vupT (qbf dead after C_q GEMM);
  //           kbf reused as vupB (kbf dead after C_kv GEMM). total 114 MB.
  u16* qbf   = (u16*)(ws);                    // 32 MB bf16 [4096,4096]
  u16* vupT  = qbf;                           //        bf16 [B,H,256,2048]
  u16* kbf   = (u16*)(ws + 33554432);         // 32 MB bf16 [4096,4096]
  u16* vupB  = kbf;                           //        bf16 [4096,4096]
  u16* q2b   = (u16*)(ws + 67108864);         // 32 MB bf16 [4096,4096]
  u16* cqb   = (u16*)(ws + 100663296);        //  4 MB bf16 [4096,512]
  u16* ckvb  = (u16*)(ws + 104857600);        //  2 MB bf16 [4096,256]
  u16* wqdT  = (u16*)(ws + 106954752);        //  4 MB bf16 [512,4096]
  u16* wqkT  = (u16*)(ws + 111149056);        //  4 MB bf16 [4096,512]
  u16* wkvdT = (u16*)(ws + 115343360);        //  2 MB bf16 [256,4096]
  u16* wvuT  = (u16*)(ws + 117440512);        //  2 MB bf16 [4096,256]

  // input converts (Q and K in one launch)
  cvt_bf16_2<<<dim3(32768), 256, 0, stream>>>(Q, qbf, Kin, kbf, 4194304);
  // weight convert+transpose: [R,C] fp32 -> [C,R] bf16
  cvt_transpose<<<dim3(128, 16), 256, 0, stream>>>(Wq_d,  wqdT,  4096, 512);
  cvt_transpose<<<dim3(16, 128), 256, 0, stream>>>(W_qk,  wqkT,  512, 4096);
  cvt_transpose<<<dim3(128, 8),  256, 0, stream>>>(Wkv_d, wkvdT, 4096, 256);
  cvt_transpose<<<dim3(8, 128),  256, 0, stream>>>(Wv_u,  wvuT,  256, 4096);

  // C_q = Q @ Wq_d [4096,512] and C_kv = K @ Wkv_d [4096,256], K=4096, one launch
  gemm_qkv<<<dim3(12, 32), 256, 0, stream>>>(qbf, wqdT, cqb, kbf, wkvdT, ckvb);
  // Q2 = C_q @ W_qk          [4096,4096] K=512
  gemm_bt<<<dim3(32, 32), 256, 0, stream>>>(cqb, wqkT, q2b, 4096, 4096, 512);
  // V_up = C_kv @ Wv_u       [4096,4096] K=256   (overwrites kbf region)
  gemm_bt<<<dim3(32, 32), 256, 0, stream>>>(ckvb, wvuT, vupB, 4096, 4096, 256);
  // V transpose (overwrites qbf region)
  transpose_v<<<dim3(32, 4, 32), 256, 0, stream>>>(vupB, vupT);
  // flash attention: QBLK=64 -> 32 n-blocks x 32 bh = 1024 blocks (XCD-swizzled)
  flash_mfma<<<dim3(1024), 256, 0, stream>>>(q2b, ckvb, vupT, out);
}